// Round 1
// baseline (416.403 us; speedup 1.0000x reference)
//
#include <hip/hip_runtime.h>
#include <hip/hip_bf16.h>
#include <math.h>

typedef __bf16 bf16;
typedef __bf16 bf16x8 __attribute__((ext_vector_type(8)));
typedef float f32x4 __attribute__((ext_vector_type(4)));

#define BB 64
#define NN 256
#define DD 768
#define MM (BB*NN)           // 16384
#define KCAT (4*NN)          // 1024
#define WSZ (DD*DD)          // 589824

// ---------------- async global->LDS (16B per lane) ----------------
__device__ __forceinline__ void async16(const void* g, void* l) {
  __builtin_amdgcn_global_load_lds((__attribute__((address_space(1))) void*)g,
                                   (__attribute__((address_space(3))) void*)l,
                                   16, 0, 0);
}

// stage a 128x32 bf16 tile (row-major, row stride ld elements) into 8KB LDS
// 8 chunks of 1024B; wave wv handles chunks {2wv, 2wv+1}
__device__ __forceinline__ void stage_tile(const bf16* gsrc, int ld, char* ldst,
                                           int wv, int lane) {
#pragma unroll
  for (int cc = 0; cc < 2; ++cc) {
    int c = wv * 2 + cc;
    int row = c * 16 + (lane >> 2);
    int col = (lane & 3) * 8;
    async16(gsrc + (size_t)row * ld + col, ldst + c * 1024);
  }
}

// one BK=32 step: A tile [128][32], B tile [128][32] (B rows = output cols)
__device__ __forceinline__ void mma_step(const char* lA, const char* lB,
                                         f32x4 acc[4][4], int lane, int wr, int wc) {
  bf16x8 af[4], bfr[4];
  int rbase = wr * 64 + (lane & 15);
  int cbase = wc * 64 + (lane & 15);
  int ko = (lane >> 4) * 8;
#pragma unroll
  for (int r = 0; r < 4; ++r)
    af[r] = *(const bf16x8*)(lA + (((rbase + r * 16) * 32) + ko) * 2);
#pragma unroll
  for (int c = 0; c < 4; ++c)
    bfr[c] = *(const bf16x8*)(lB + (((cbase + c * 16) * 32) + ko) * 2);
#pragma unroll
  for (int r = 0; r < 4; ++r)
#pragma unroll
    for (int c = 0; c < 4; ++c)
      acc[r][c] = __builtin_amdgcn_mfma_f32_16x16x32_bf16(af[r], bfr[c], acc[r][c], 0, 0, 0);
}

// ---------------- K0: dw = sigmoid(node.Wq+bq), node->bf16, all_weight ----------------
__global__ void k_prep(const float* __restrict__ node, const float* __restrict__ Wq,
                       const float* __restrict__ bq, bf16* __restrict__ node_bf,
                       float* __restrict__ dw, float* __restrict__ allw) {
  int lane = threadIdx.x & 63, wv = threadIdx.x >> 6;
  int row = blockIdx.x * 4 + wv;                 // 0..16383
  const float* nr = node + (size_t)row * DD;
  bf16* nb = node_bf + (size_t)row * DD;
  float s = 0.f;
#pragma unroll
  for (int k = 0; k < DD / 64; ++k) {
    int idx = lane + k * 64;
    float v = nr[idx];
    nb[idx] = (bf16)v;
    s += v * Wq[idx];
  }
#pragma unroll
  for (int off = 32; off; off >>= 1) s += __shfl_down(s, off);
  if (lane == 0) {
    float z = s + bq[0];
    float d = 1.f / (1.f + expf(-z));
    dw[row] = d;
    allw[row] = d;
  }
}

// ---------------- K0c: combine + cast weights to bf16 ----------------
__global__ void k_weights(const float* __restrict__ Ws,
                          const float* __restrict__ Wa, const float* __restrict__ Wp,
                          const float* __restrict__ Wap, const float* __restrict__ Wpp,
                          const float* __restrict__ Wa2, const float* __restrict__ Wp2,
                          const float* __restrict__ Wap2, const float* __restrict__ Wpp2,
                          bf16* __restrict__ Wself, bf16* __restrict__ Wrel) {
  int i = blockIdx.x * blockDim.x + threadIdx.x;   // 0..589823
  Wself[i] = (bf16)Ws[i];
  Wrel[i]            = (bf16)(Wa[i] + Wa2[i]);
  Wrel[i + WSZ]      = (bf16)(Wp[i] + Wp2[i]);
  Wrel[i + 2 * WSZ]  = (bf16)(Wap[i] + Wap2[i]);
  Wrel[i + 3 * WSZ]  = (bf16)(Wpp[i] + Wpp2[i]);
}

// ---------------- K0b: nw (4 relations, K-concat) + 1/denom ----------------
__global__ void k_graph(const int* __restrict__ mask, const int* __restrict__ arg,
                        const int* __restrict__ pun, const float* __restrict__ dw,
                        bf16* __restrict__ nw, float* __restrict__ rdenom) {
  int b = blockIdx.x >> 8, i = blockIdx.x & 255, j = threadIdx.x;
  float mi = (float)mask[b * NN + i];
  float mj = (float)mask[b * NN + j];
  float dd = (i == j) ? 0.f : mi * mj;
  size_t gb = (size_t)b * NN * NN;
  float a  = (float)arg[gb + i * NN + j];
  float p  = (float)pun[gb + i * NN + j];
  float at = (float)arg[gb + j * NN + i];
  float pt = (float)pun[gb + j * NN + i];
  float ga = dd * a, gp = dd * p, gar = dd * dd * at, gpr = dd * dd * pt;
  float dwj = dw[b * NN + j];
  size_t nb = ((size_t)(b * NN + i)) * KCAT;
  nw[nb + j]          = (bf16)(dwj * ga);
  nw[nb + NN + j]     = (bf16)(dwj * gp);
  nw[nb + 2 * NN + j] = (bf16)(dwj * gar);
  nw[nb + 3 * NN + j] = (bf16)(dwj * gpr);
  __shared__ float red[256];
  red[j] = ga + gp + gar + gpr;
  __syncthreads();
  for (int off = 128; off > 0; off >>= 1) {
    if (j < off) red[j] += red[j + off];
    __syncthreads();
  }
  if (j == 0) {
    float neigh = red[0];
    float denom = (neigh >= 1.f) ? neigh : 1.f;
    rdenom[b * NN + i] = 1.f / denom;
  }
}

// ---------------- K1a: self_info = node @ Ws^T + bs  (fp32 -> d_out) ----------------
__global__ __launch_bounds__(256) void k_gemm_self(const bf16* __restrict__ A,
                                                   const bf16* __restrict__ Bw,
                                                   const float* __restrict__ bs,
                                                   float* __restrict__ out) {
  __shared__ __align__(16) char lA[8192];
  __shared__ __align__(16) char lB[8192];
  int tid = threadIdx.x, lane = tid & 63, wv = tid >> 6, wr = wv >> 1, wc = wv & 1;
  int m0 = blockIdx.y * 128, n0 = blockIdx.x * 128;
  f32x4 z = {0.f, 0.f, 0.f, 0.f};
  f32x4 acc[4][4];
#pragma unroll
  for (int r = 0; r < 4; ++r)
#pragma unroll
    for (int c = 0; c < 4; ++c) acc[r][c] = z;
  for (int k0 = 0; k0 < DD; k0 += 32) {
    __syncthreads();
    stage_tile(A + (size_t)m0 * DD + k0, DD, lA, wv, lane);
    stage_tile(Bw + (size_t)n0 * DD + k0, DD, lB, wv, lane);
    __builtin_amdgcn_s_waitcnt(0);
    __syncthreads();
    mma_step(lA, lB, acc, lane, wr, wc);
  }
  int rowb = m0 + wr * 64 + (lane >> 4) * 4;
  int colb = n0 + wc * 64 + (lane & 15);
#pragma unroll
  for (int c = 0; c < 4; ++c) {
    int col = colb + c * 16;
    float bsv = bs[col];
#pragma unroll
    for (int r = 0; r < 4; ++r)
#pragma unroll
      for (int q = 0; q < 4; ++q) {
        int row = rowb + r * 16 + q;
        out[(size_t)row * DD + col] = acc[r][c][q] + bsv;
      }
  }
}

// ---------------- K1b: projT[X][b][d][j] = (node @ Wrel_X^T)^T  (bf16) ----------------
__global__ __launch_bounds__(256) void k_gemm_rel(const bf16* __restrict__ Wrel,
                                                  const bf16* __restrict__ Bn,
                                                  bf16* __restrict__ projT) {
  __shared__ __align__(16) char lA[8192];
  __shared__ __align__(16) char lB[8192];
  int tid = threadIdx.x, lane = tid & 63, wv = tid >> 6, wr = wv >> 1, wc = wv & 1;
  int d0 = blockIdx.y * 128;     // row dim: 4*768 = 3072 (relation-concat d)
  int m0 = blockIdx.x * 128;     // col dim: 16384 (b,j)
  f32x4 z = {0.f, 0.f, 0.f, 0.f};
  f32x4 acc[4][4];
#pragma unroll
  for (int r = 0; r < 4; ++r)
#pragma unroll
    for (int c = 0; c < 4; ++c) acc[r][c] = z;
  for (int k0 = 0; k0 < DD; k0 += 32) {
    __syncthreads();
    stage_tile(Wrel + (size_t)d0 * DD + k0, DD, lA, wv, lane);
    stage_tile(Bn + (size_t)m0 * DD + k0, DD, lB, wv, lane);
    __builtin_amdgcn_s_waitcnt(0);
    __syncthreads();
    mma_step(lA, lB, acc, lane, wr, wc);
  }
  int X = d0 / DD;                       // 128 | 768, tile within one relation chunk
  int b = m0 >> 8;                       // 128-col tile within one batch
  int dbase = (d0 % DD) + wr * 64 + (lane >> 4) * 4;
  int jbase = (m0 & 255) + wc * 64 + (lane & 15);
  size_t base = ((size_t)X * BB + b) * DD * NN;
#pragma unroll
  for (int r = 0; r < 4; ++r)
#pragma unroll
    for (int q = 0; q < 4; ++q) {
      int d = dbase + r * 16 + q;
#pragma unroll
      for (int c = 0; c < 4; ++c) {
        int j = jbase + c * 16;
        projT[base + (size_t)d * NN + j] = (bf16)acc[r][c][q];
      }
    }
}

// ---------------- K2: out = relu(self + (nw @ projcat)/denom) ----------------
__global__ __launch_bounds__(256) void k_gemm_agg(const bf16* __restrict__ nw,
                                                  const bf16* __restrict__ projT,
                                                  const float* __restrict__ rdenom,
                                                  float* __restrict__ out) {
  __shared__ __align__(16) char lA[8192];
  __shared__ __align__(16) char lB[8192];
  int tid = threadIdx.x, lane = tid & 63, wv = tid >> 6, wr = wv >> 1, wc = wv & 1;
  int b = blockIdx.y;
  int ti = blockIdx.x / 6, td = blockIdx.x % 6;
  int i0 = ti * 128, d0 = td * 128;
  const bf16* Abase = nw + ((size_t)b * NN + i0) * KCAT;
  f32x4 z = {0.f, 0.f, 0.f, 0.f};
  f32x4 acc[4][4];
#pragma unroll
  for (int r = 0; r < 4; ++r)
#pragma unroll
    for (int c = 0; c < 4; ++c) acc[r][c] = z;
  for (int k0 = 0; k0 < KCAT; k0 += 32) {
    int X = k0 >> 8, j0 = k0 & 255;
    const bf16* Bt = projT + ((size_t)X * BB + b) * DD * NN + (size_t)d0 * NN + j0;
    __syncthreads();
    stage_tile(Abase + k0, KCAT, lA, wv, lane);
    stage_tile(Bt, NN, lB, wv, lane);
    __builtin_amdgcn_s_waitcnt(0);
    __syncthreads();
    mma_step(lA, lB, acc, lane, wr, wc);
  }
  int ibase = i0 + wr * 64 + (lane >> 4) * 4;
  int dbase = d0 + wc * 64 + (lane & 15);
#pragma unroll
  for (int r = 0; r < 4; ++r)
#pragma unroll
    for (int q = 0; q < 4; ++q) {
      int i = ibase + r * 16 + q;
      int m = b * NN + i;
      float rd = rdenom[m];
#pragma unroll
      for (int c = 0; c < 4; ++c) {
        int d = dbase + c * 16;
        size_t o = (size_t)m * DD + d;
        float v = out[o] + acc[r][c][q] * rd;
        out[o] = fmaxf(v, 0.f);
      }
    }
}

// ---------------- launch ----------------
extern "C" void kernel_launch(void* const* d_in, const int* in_sizes, int n_in,
                              void* d_out, int out_size, void* d_ws, size_t ws_size,
                              hipStream_t stream) {
  const float* node = (const float*)d_in[0];
  const int* mask   = (const int*)d_in[1];
  const int* arg    = (const int*)d_in[2];
  const int* pun    = (const int*)d_in[3];
  const float* Wq   = (const float*)d_in[4];
  const float* bq   = (const float*)d_in[5];
  const float* Ws   = (const float*)d_in[6];
  const float* bs   = (const float*)d_in[7];
  const float* Wa   = (const float*)d_in[8];
  const float* Wp   = (const float*)d_in[9];
  const float* Wap  = (const float*)d_in[10];
  const float* Wpp  = (const float*)d_in[11];
  const float* Wa2  = (const float*)d_in[12];
  const float* Wp2  = (const float*)d_in[13];
  const float* Wap2 = (const float*)d_in[14];
  const float* Wpp2 = (const float*)d_in[15];

  float* out  = (float*)d_out;              // node: 16384*768 fp32
  float* allw = out + (size_t)MM * DD;      // all_weight: 16384 fp32

  char* ws = (char*)d_ws;
  bf16* node_bf = (bf16*)ws;                              // 25165824 B
  float* dw     = (float*)(ws + 25165824);                // 65536 B
  float* rden   = (float*)(ws + 25231360);                // 65536 B
  bf16* Wself   = (bf16*)(ws + 25296896);                 // 1179648 B
  bf16* Wrel    = (bf16*)(ws + 26476544);                 // 4718592 B
  bf16* nw      = (bf16*)(ws + 31195136);                 // 33554432 B
  bf16* projT   = (bf16*)(ws + 64749568);                 // 100663296 B -> total 165412864 B
  (void)ws_size; (void)in_sizes; (void)n_in; (void)out_size;

  k_prep<<<MM / 4, 256, 0, stream>>>(node, Wq, bq, node_bf, dw, allw);
  k_weights<<<WSZ / 256, 256, 0, stream>>>(Ws, Wa, Wp, Wap, Wpp, Wa2, Wp2, Wap2, Wpp2,
                                           Wself, Wrel);
  k_graph<<<MM, 256, 0, stream>>>(mask, arg, pun, dw, nw, rden);
  k_gemm_self<<<dim3(6, 128), 256, 0, stream>>>(node_bf, Wself, bs, out);
  k_gemm_rel<<<dim3(128, 24), 256, 0, stream>>>(Wrel, node_bf, projT);
  k_gemm_agg<<<dim3(12, 64), 256, 0, stream>>>(nw, projT, rden, out);
}